// Round 1
// baseline (4909.938 us; speedup 1.0000x reference)
//
#include <hip/hip_runtime.h>
#include <math.h>

#define B    128
#define NLOC 196
#define DV   512
#define EMB  512
#define HD   1024
#define VV   10000
#define TT   20
#define G4   4096   // 4*HD

// ---------------- small kernels ----------------

__global__ void fmean_kernel(const float* __restrict__ feat, float* __restrict__ fmean) {
    int idx = blockIdx.x * blockDim.x + threadIdx.x;   // B*DV
    if (idx >= B * DV) return;
    int b = idx / DV, d = idx % DV;
    const float* p = feat + (size_t)b * NLOC * DV + d;
    float s = 0.f;
    for (int n = 0; n < NLOC; ++n) s += p[(size_t)n * DV];
    fmean[idx] = s * (1.0f / NLOC);
}

__global__ void attv_kernel(const float* __restrict__ feat, const float* __restrict__ wv,
                            const float* __restrict__ bv, float* __restrict__ attv) {
    // one wave (64 lanes) per (b,n) row
    int row  = blockIdx.x;         // B*NLOC
    int lane = threadIdx.x;        // 64
    const float* p = feat + (size_t)row * DV;
    float s = 0.f;
    for (int k = lane; k < DV; k += 64) s += p[k] * wv[k];
    for (int off = 32; off > 0; off >>= 1) s += __shfl_down(s, off);
    if (lane == 0) attv[row] = s + bv[0];
}

__global__ void alpha_kernel(const float* __restrict__ attv, float* __restrict__ alpha) {
    int b   = blockIdx.x;          // B
    int tid = threadIdx.x;         // 256
    __shared__ float red[256];
    float v = (tid < NLOC) ? attv[b * NLOC + tid] : -1e30f;
    red[tid] = v; __syncthreads();
    for (int s = 128; s > 0; s >>= 1) { if (tid < s) red[tid] = fmaxf(red[tid], red[tid + s]); __syncthreads(); }
    float m = red[0]; __syncthreads();
    float e = (tid < NLOC) ? expf(v - m) : 0.f;
    red[tid] = e; __syncthreads();
    for (int s = 128; s > 0; s >>= 1) { if (tid < s) red[tid] += red[tid + s]; __syncthreads(); }
    float sum = red[0];
    if (tid < NLOC) alpha[b * NLOC + tid] = e / sum;
}

__global__ void ctx_kernel(const float* __restrict__ feat, const float* __restrict__ alpha,
                           float* __restrict__ ctx) {
    int idx = blockIdx.x * blockDim.x + threadIdx.x;   // B*DV
    if (idx >= B * DV) return;
    int b = idx / DV, d = idx % DV;
    const float* p = feat + (size_t)b * NLOC * DV + d;
    const float* a = alpha + b * NLOC;
    float s = 0.f;
    for (int n = 0; n < NLOC; ++n) s += a[n] * p[(size_t)n * DV];
    ctx[idx] = s;
}

__global__ void emb_gather_kernel(const int* __restrict__ captions, const float* __restrict__ table,
                                  float* __restrict__ emb_mat) {
    size_t idx = (size_t)blockIdx.x * blockDim.x + threadIdx.x;   // T*B*EMB
    if (idx >= (size_t)TT * B * EMB) return;
    int k = (int)(idx % EMB);
    int r = (int)(idx / EMB);      // r = t*B + b
    int t = r / B, b = r % B;
    int cap = captions[b * TT + t];
    emb_mat[idx] = table[(size_t)cap * EMB + k];
}

// ---------------- generic fp32 tiled matmul: C[M,N] = A[M,K] @ Bw[N,K]^T (+bias0+bias1) ----------------
// A row stride lda, Bw row stride ldb (column offset folded into pointer), C row stride ldc.
__global__ __launch_bounds__(256)
void matmul_abt(const float* __restrict__ A, const float* __restrict__ Bw,
                float* __restrict__ C,
                const float* __restrict__ bias0, const float* __restrict__ bias1,
                int M, int N, int K, int lda, int ldb, int ldc) {
    const int BM = 64, BN = 64, BK = 16;
    __shared__ float As[BK][BM];
    __shared__ float Bs[BK][BN];
    int tid = threadIdx.x;
    int tx = tid % 16, ty = tid / 16;
    int m0 = blockIdx.y * BM, n0 = blockIdx.x * BN;
    float acc[4][4] = {};
    for (int k0 = 0; k0 < K; k0 += BK) {
        #pragma unroll
        for (int i = 0; i < 4; ++i) {
            int idx = tid + i * 256;
            int m = idx / BK, k = idx % BK;
            int gm = m0 + m;
            As[k][m] = (gm < M) ? A[(size_t)gm * lda + k0 + k] : 0.f;
        }
        #pragma unroll
        for (int i = 0; i < 4; ++i) {
            int idx = tid + i * 256;
            int n = idx / BK, k = idx % BK;
            int gn = n0 + n;
            Bs[k][n] = (gn < N) ? Bw[(size_t)gn * ldb + k0 + k] : 0.f;
        }
        __syncthreads();
        #pragma unroll
        for (int kk = 0; kk < BK; ++kk) {
            float a[4], bb[4];
            #pragma unroll
            for (int i = 0; i < 4; ++i) a[i] = As[kk][ty + 16 * i];
            #pragma unroll
            for (int j = 0; j < 4; ++j) bb[j] = Bs[kk][tx + 16 * j];
            #pragma unroll
            for (int i = 0; i < 4; ++i)
                #pragma unroll
                for (int j = 0; j < 4; ++j) acc[i][j] += a[i] * bb[j];
        }
        __syncthreads();
    }
    #pragma unroll
    for (int i = 0; i < 4; ++i) {
        int gm = m0 + ty + 16 * i;
        if (gm >= M) continue;
        #pragma unroll
        for (int j = 0; j < 4; ++j) {
            int gn = n0 + tx + 16 * j;
            if (gn >= N) continue;
            float v = acc[i][j];
            if (bias0) v += bias0[gn];
            if (bias1) v += bias1[gn];
            C[(size_t)gm * ldc + gn] = v;
        }
    }
}

// ---------------- LSTM elementwise step ----------------
__global__ void lstm_kernel(const float* __restrict__ hW, const float* __restrict__ pre_t,
                            const float* __restrict__ gctx,
                            float* __restrict__ h, float* __restrict__ c,
                            float* __restrict__ Hall_t) {
    int idx = blockIdx.x * blockDim.x + threadIdx.x;   // B*HD
    if (idx >= B * HD) return;
    int b = idx / HD, j = idx % HD;
    int base = b * G4 + j;
    float gi = hW[base]          + pre_t[base]          + gctx[base];
    float gf = hW[base + HD]     + pre_t[base + HD]     + gctx[base + HD];
    float gg = hW[base + 2 * HD] + pre_t[base + 2 * HD] + gctx[base + 2 * HD];
    float go = hW[base + 3 * HD] + pre_t[base + 3 * HD] + gctx[base + 3 * HD];
    float si = 1.f / (1.f + expf(-gi));
    float sf = 1.f / (1.f + expf(-gf));
    float so = 1.f / (1.f + expf(-go));
    float cn = sf * c[idx] + si * tanhf(gg);
    float hn = so * tanhf(cn);
    c[idx] = cn;
    h[idx] = hn;
    Hall_t[idx] = hn;
}

// ---------------- fused log_softmax + softmax over V, in-place on words ----------------
__global__ void softmax_kernel(float* __restrict__ words_logout, float* __restrict__ smout) {
    int r = blockIdx.x;            // T*B rows
    int tid = threadIdx.x;         // 512
    float* row = words_logout + (size_t)r * VV;
    __shared__ float red[512];
    float m = -1e30f;
    for (int i = tid; i < VV; i += 512) m = fmaxf(m, row[i]);
    red[tid] = m; __syncthreads();
    for (int s = 256; s > 0; s >>= 1) { if (tid < s) red[tid] = fmaxf(red[tid], red[tid + s]); __syncthreads(); }
    m = red[0]; __syncthreads();
    float sum = 0.f;
    for (int i = tid; i < VV; i += 512) sum += expf(row[i] - m);
    red[tid] = sum; __syncthreads();
    for (int s = 256; s > 0; s >>= 1) { if (tid < s) red[tid] += red[tid + s]; __syncthreads(); }
    sum = red[0];
    float lz = logf(sum);
    for (int i = tid; i < VV; i += 512) {
        float x = row[i];
        float e = expf(x - m);
        smout[(size_t)r * VV + i] = e / sum;
        row[i] = x - m - lz;       // log_softmax, overwrites words after read
    }
}

// ---------------- launch ----------------
extern "C" void kernel_launch(void* const* d_in, const int* in_sizes, int n_in,
                              void* d_out, int out_size, void* d_ws, size_t ws_size,
                              hipStream_t stream) {
    const float* features    = (const float*)d_in[0];
    const int*   captions    = (const int*)  d_in[1];
    const float* W_init_h    = (const float*)d_in[2];
    const float* W_init_c    = (const float*)d_in[3];
    const float* W_attn_v    = (const float*)d_in[4];
    const float* b_attn_v    = (const float*)d_in[5];
    // d_in[6], d_in[7] (W_attn_h, b_attn_h) are mathematically dead: softmax shift-invariance.
    const float* embed_table = (const float*)d_in[8];
    const float* W_ih        = (const float*)d_in[9];
    const float* W_hh        = (const float*)d_in[10];
    const float* b_ih        = (const float*)d_in[11];
    const float* b_hh        = (const float*)d_in[12];
    const float* W_out       = (const float*)d_in[13];
    const float* b_out       = (const float*)d_in[14];

    float* out   = (float*)d_out;
    float* words = out;                                   // first half: words -> log_softmax (in place)
    float* smx   = out + (size_t)TT * B * VV;             // second half: softmax (scratch until then)

    // small scratch in d_ws
    float* ws      = (float*)d_ws;
    float* fmean   = ws;                                  // B*DV
    float* attv    = fmean + (size_t)B * DV;              // B*NLOC
    float* alpha   = attv + (size_t)B * NLOC;             // B*NLOC
    float* ctx     = alpha + (size_t)B * NLOC;            // B*DV
    float* gctx    = ctx + (size_t)B * DV;                // B*G4
    float* h       = gctx + (size_t)B * G4;               // B*HD
    float* c       = h + (size_t)B * HD;                  // B*HD
    float* hW      = c + (size_t)B * HD;                  // B*G4
    float* emb_mat = hW + (size_t)B * G4;                 // T*B*EMB

    // big scratch lives in d_out's second half (overwritten only by final softmax writes)
    float* gate_pre = smx;                                // T*B*G4 = 10,485,760 floats
    float* Hall     = gate_pre + (size_t)TT * B * G4;     // T*B*HD =  2,621,440 floats

    // ---- phase 1: everything time-parallel ----
    fmean_kernel<<<(B * DV + 255) / 256, 256, 0, stream>>>(features, fmean);
    attv_kernel<<<B * NLOC, 64, 0, stream>>>(features, W_attn_v, b_attn_v, attv);
    alpha_kernel<<<B, 256, 0, stream>>>(attv, alpha);
    ctx_kernel<<<(B * DV + 255) / 256, 256, 0, stream>>>(features, alpha, ctx);
    emb_gather_kernel<<<((size_t)TT * B * EMB + 255) / 256, 256, 0, stream>>>(captions, embed_table, emb_mat);

    // h0 = fmean @ W_init_h^T ; c0 = fmean @ W_init_c^T
    matmul_abt<<<dim3(HD / 64, (B + 63) / 64), 256, 0, stream>>>(
        fmean, W_init_h, h, nullptr, nullptr, B, HD, DV, DV, DV, HD);
    matmul_abt<<<dim3(HD / 64, (B + 63) / 64), 256, 0, stream>>>(
        fmean, W_init_c, c, nullptr, nullptr, B, HD, DV, DV, DV, HD);
    // gate_ctx = ctx @ W_ih[:, :512]^T + b_ih + b_hh
    matmul_abt<<<dim3(G4 / 64, (B + 63) / 64), 256, 0, stream>>>(
        ctx, W_ih, gctx, b_ih, b_hh, B, G4, DV, DV, DV + EMB, G4);
    // gate_pre = emb_mat @ W_ih[:, 512:]^T   (all T at once)
    matmul_abt<<<dim3(G4 / 64, (TT * B + 63) / 64), 256, 0, stream>>>(
        emb_mat, W_ih + DV, gate_pre, nullptr, nullptr, TT * B, G4, EMB, EMB, DV + EMB, G4);

    // ---- phase 2: sequential recurrence (only h @ W_hh^T is on the critical path) ----
    for (int t = 0; t < TT; ++t) {
        matmul_abt<<<dim3(G4 / 64, (B + 63) / 64), 256, 0, stream>>>(
            h, W_hh, hW, nullptr, nullptr, B, G4, HD, HD, HD, G4);
        lstm_kernel<<<(B * HD + 255) / 256, 256, 0, stream>>>(
            hW, gate_pre + (size_t)t * B * G4, gctx, h, c, Hall + (size_t)t * B * HD);
    }

    // ---- phase 3: words = Hall @ W_out^T + b_out, then fused log_softmax/softmax ----
    matmul_abt<<<dim3((VV + 63) / 64, (TT * B + 63) / 64), 256, 0, stream>>>(
        Hall, W_out, words, b_out, nullptr, TT * B, VV, HD, HD, HD, VV);
    softmax_kernel<<<TT * B, 512, 0, stream>>>(words, smx);
}

// Round 2
// 687.767 us; speedup vs baseline: 7.1390x; 7.1390x over previous
//
#include <hip/hip_runtime.h>
#include <math.h>

#define B    128
#define NLOC 196
#define DV   512
#define EMB  512
#define HD   1024
#define VV   10000
#define TT   20
#define G4   4096   // 4*HD
#define VPAD 10112  // 79*128

typedef short bf16x8 __attribute__((ext_vector_type(8)));
typedef float f32x4  __attribute__((ext_vector_type(4)));

__device__ __forceinline__ unsigned short f2bf(float x) {
    unsigned u = __builtin_bit_cast(unsigned, x);
    unsigned r = (u + 0x7fffu + ((u >> 16) & 1u)) >> 16;
    return (unsigned short)r;
}

__device__ __forceinline__ void gload_lds16(const void* g, void* lds) {
    __builtin_amdgcn_global_load_lds(
        (const __attribute__((address_space(1))) void*)g,
        (__attribute__((address_space(3))) void*)lds, 16, 0, 0);
}

// ---------------- small kernels ----------------

__global__ void fmean_kernel(const float* __restrict__ feat, short* __restrict__ fmean_b) {
    int idx = blockIdx.x * blockDim.x + threadIdx.x;   // B*DV
    if (idx >= B * DV) return;
    int b = idx / DV, d = idx % DV;
    const float* p = feat + (size_t)b * NLOC * DV + d;
    float s = 0.f;
    for (int n = 0; n < NLOC; ++n) s += p[(size_t)n * DV];
    fmean_b[idx] = (short)f2bf(s * (1.0f / NLOC));
}

__global__ void attv_kernel(const float* __restrict__ feat, const float* __restrict__ wv,
                            const float* __restrict__ bv, float* __restrict__ attv) {
    int row  = blockIdx.x;         // B*NLOC
    int lane = threadIdx.x;        // 64
    const float* p = feat + (size_t)row * DV;
    float s = 0.f;
    for (int k = lane; k < DV; k += 64) s += p[k] * wv[k];
    for (int off = 32; off > 0; off >>= 1) s += __shfl_down(s, off);
    if (lane == 0) attv[row] = s + bv[0];
}

__global__ void alpha_kernel(const float* __restrict__ attv, float* __restrict__ alpha) {
    int b   = blockIdx.x;          // B
    int tid = threadIdx.x;         // 256
    __shared__ float red[256];
    float v = (tid < NLOC) ? attv[b * NLOC + tid] : -1e30f;
    red[tid] = v; __syncthreads();
    for (int s = 128; s > 0; s >>= 1) { if (tid < s) red[tid] = fmaxf(red[tid], red[tid + s]); __syncthreads(); }
    float m = red[0]; __syncthreads();
    float e = (tid < NLOC) ? expf(v - m) : 0.f;
    red[tid] = e; __syncthreads();
    for (int s = 128; s > 0; s >>= 1) { if (tid < s) red[tid] += red[tid + s]; __syncthreads(); }
    float sum = red[0];
    if (tid < NLOC) alpha[b * NLOC + tid] = e / sum;
}

__global__ void ctx_kernel(const float* __restrict__ feat, const float* __restrict__ alpha,
                           short* __restrict__ ctx_b) {
    int idx = blockIdx.x * blockDim.x + threadIdx.x;   // B*DV
    if (idx >= B * DV) return;
    int b = idx / DV, d = idx % DV;
    const float* p = feat + (size_t)b * NLOC * DV + d;
    const float* a = alpha + b * NLOC;
    float s = 0.f;
    for (int n = 0; n < NLOC; ++n) s += a[n] * p[(size_t)n * DV];
    ctx_b[idx] = (short)f2bf(s);
}

__global__ void emb_gather_kernel(const int* __restrict__ captions, const float* __restrict__ table,
                                  short* __restrict__ emb_b) {
    size_t idx = (size_t)blockIdx.x * blockDim.x + threadIdx.x;   // T*B*EMB
    if (idx >= (size_t)TT * B * EMB) return;
    int k = (int)(idx % EMB);
    int r = (int)(idx / EMB);      // r = t*B + b
    int t = r / B, b = r % B;
    int cap = captions[b * TT + t];
    emb_b[idx] = (short)f2bf(table[(size_t)cap * EMB + k]);
}

__global__ void f2bf_pad_kernel(const float* __restrict__ in, short* __restrict__ out,
                                size_t n, size_t npad) {
    size_t i = (size_t)blockIdx.x * blockDim.x + threadIdx.x;
    if (i >= npad) return;
    out[i] = (i < n) ? (short)f2bf(in[i]) : (short)0;
}

__global__ void hcvt_kernel(const float* __restrict__ h, short* __restrict__ h_bf) {
    int idx = blockIdx.x * blockDim.x + threadIdx.x;   // B*HD
    if (idx >= B * HD) return;
    h_bf[idx] = (short)f2bf(h[idx]);
}

// ---------------- bf16 MFMA GEMM: C[M,N] = A[M,K] @ Bw[N,K]^T (+bias0+bias1) ----------------
// BM fixed 128, BK=32. Template BN + wave layout. M must be multiple of 128, K of 32.
// Bw must be readable up to ceil(N/BN)*BN rows (pad weights). Stores guarded by N.
template<int BN, int WR, int WC>
__global__ __launch_bounds__(256)
void gemm_bf16(const short* __restrict__ A, const short* __restrict__ Bw,
               float* __restrict__ C,
               const float* __restrict__ bias0, const float* __restrict__ bias1,
               int M, int N, int K, int lda, int ldb, int ldc) {
    constexpr int BM = 128;
    constexpr int BK = 32;
    constexpr int WM = BM / WR;
    constexpr int WN = BN / WC;
    constexpr int FM = WM / 16;
    constexpr int FN = WN / 16;
    __shared__ short As[BM * BK];
    __shared__ short Bs[BN * BK];
    const int tid  = threadIdx.x;
    const int wave = tid >> 6, lane = tid & 63;
    const int wr = wave / WC, wc = wave % WC;
    const int m0 = blockIdx.y * BM, n0 = blockIdx.x * BN;
    const int laneoff = lane * 16;   // byte offset within wave segment

    f32x4 acc[FM][FN] = {};

    for (int k0 = 0; k0 < K; k0 += BK) {
        // stage A: BM*BK*2 = 8192 B = 2 rounds x 256 thr x 16 B
        #pragma unroll
        for (int r = 0; r < 2; ++r) {
            int o   = r * 4096 + wave * 1024 + laneoff;  // byte offset in As
            int row = o >> 6;                            // 64 B per row
            int col = (o & 63) >> 1;
            gload_lds16(A + (size_t)(m0 + row) * lda + k0 + col,
                        (char*)As + r * 4096 + wave * 1024);
        }
        // stage B: BN*BK*2 bytes
        constexpr int BBYTES = BN * BK * 2;
        if constexpr (BBYTES >= 4096) {
            #pragma unroll
            for (int r = 0; r < BBYTES / 4096; ++r) {
                int o   = r * 4096 + wave * 1024 + laneoff;
                int row = o >> 6;
                int col = (o & 63) >> 1;
                gload_lds16(Bw + (size_t)(n0 + row) * ldb + k0 + col,
                            (char*)Bs + r * 4096 + wave * 1024);
            }
        } else {
            constexpr int NW = BBYTES / 1024;   // waves participating
            if (wave < NW) {
                int o   = wave * 1024 + laneoff;
                int row = o >> 6;
                int col = (o & 63) >> 1;
                gload_lds16(Bw + (size_t)(n0 + row) * ldb + k0 + col,
                            (char*)Bs + wave * 1024);
            }
        }
        __syncthreads();

        bf16x8 a[FM], b[FN];
        const int kfr = (lane >> 4) * 8;
        #pragma unroll
        for (int i = 0; i < FM; ++i) {
            int row = wr * WM + i * 16 + (lane & 15);
            a[i] = *(const bf16x8*)&As[row * BK + kfr];
        }
        #pragma unroll
        for (int j = 0; j < FN; ++j) {
            int row = wc * WN + j * 16 + (lane & 15);
            b[j] = *(const bf16x8*)&Bs[row * BK + kfr];
        }
        #pragma unroll
        for (int i = 0; i < FM; ++i)
            #pragma unroll
            for (int j = 0; j < FN; ++j)
                acc[i][j] = __builtin_amdgcn_mfma_f32_16x16x32_bf16(a[i], b[j], acc[i][j], 0, 0, 0);
        __syncthreads();
    }

    #pragma unroll
    for (int i = 0; i < FM; ++i) {
        #pragma unroll
        for (int j = 0; j < FN; ++j) {
            int col = n0 + wc * WN + j * 16 + (lane & 15);
            if (col >= N) continue;
            float bv = (bias0 ? bias0[col] : 0.f) + (bias1 ? bias1[col] : 0.f);
            #pragma unroll
            for (int q = 0; q < 4; ++q) {
                int row = m0 + wr * WM + i * 16 + (lane >> 4) * 4 + q;
                if (row < M) C[(size_t)row * ldc + col] = acc[i][j][q] + bv;
            }
        }
    }
}

// ---------------- LSTM elementwise step ----------------
__global__ void lstm_kernel(const float* __restrict__ hW, const float* __restrict__ pre_t,
                            const float* __restrict__ gctx,
                            float* __restrict__ c, short* __restrict__ h_bf,
                            short* __restrict__ Hall_t) {
    int idx = blockIdx.x * blockDim.x + threadIdx.x;   // B*HD
    if (idx >= B * HD) return;
    int b = idx / HD, j = idx % HD;
    int base = b * G4 + j;
    float gi = hW[base]          + pre_t[base]          + gctx[base];
    float gf = hW[base + HD]     + pre_t[base + HD]     + gctx[base + HD];
    float gg = hW[base + 2 * HD] + pre_t[base + 2 * HD] + gctx[base + 2 * HD];
    float go = hW[base + 3 * HD] + pre_t[base + 3 * HD] + gctx[base + 3 * HD];
    float si = 1.f / (1.f + expf(-gi));
    float sf = 1.f / (1.f + expf(-gf));
    float so = 1.f / (1.f + expf(-go));
    float cn = sf * c[idx] + si * tanhf(gg);
    float hn = so * tanhf(cn);
    c[idx] = cn;
    short hb = (short)f2bf(hn);
    h_bf[idx] = hb;
    Hall_t[idx] = hb;
}

// ---------------- fused log_softmax + softmax over V ----------------
__global__ void softmax_kernel(float* __restrict__ words_logout, float* __restrict__ smout) {
    int r = blockIdx.x;            // T*B rows
    int tid = threadIdx.x;         // 512
    float* row = words_logout + (size_t)r * VV;
    __shared__ float red[512];
    float m = -1e30f;
    for (int i = tid; i < VV; i += 512) m = fmaxf(m, row[i]);
    red[tid] = m; __syncthreads();
    for (int s = 256; s > 0; s >>= 1) { if (tid < s) red[tid] = fmaxf(red[tid], red[tid + s]); __syncthreads(); }
    m = red[0]; __syncthreads();
    float sum = 0.f;
    for (int i = tid; i < VV; i += 512) sum += expf(row[i] - m);
    red[tid] = sum; __syncthreads();
    for (int s = 256; s > 0; s >>= 1) { if (tid < s) red[tid] += red[tid + s]; __syncthreads(); }
    sum = red[0];
    float lz = logf(sum);
    for (int i = tid; i < VV; i += 512) {
        float x = row[i];
        float e = expf(x - m);
        smout[(size_t)r * VV + i] = e / sum;
        row[i] = x - m - lz;
    }
}

// ---------------- launch ----------------
extern "C" void kernel_launch(void* const* d_in, const int* in_sizes, int n_in,
                              void* d_out, int out_size, void* d_ws, size_t ws_size,
                              hipStream_t stream) {
    const float* features    = (const float*)d_in[0];
    const int*   captions    = (const int*)  d_in[1];
    const float* W_init_h    = (const float*)d_in[2];
    const float* W_init_c    = (const float*)d_in[3];
    const float* W_attn_v    = (const float*)d_in[4];
    const float* b_attn_v    = (const float*)d_in[5];
    // d_in[6], d_in[7] (W_attn_h, b_attn_h) dead: softmax shift-invariance.
    const float* embed_table = (const float*)d_in[8];
    const float* W_ih        = (const float*)d_in[9];
    const float* W_hh        = (const float*)d_in[10];
    const float* b_ih        = (const float*)d_in[11];
    const float* b_hh        = (const float*)d_in[12];
    const float* W_out       = (const float*)d_in[13];
    const float* b_out       = (const float*)d_in[14];

    float* out   = (float*)d_out;
    float* words = out;                        // first half (log_softmax in place)
    float* s2    = out + (size_t)TT * B * VV;  // second half: scratch until final softmax

    // second-half big scratch (all dead before softmax_kernel writes smx here)
    float* gate_pre = s2;                                        // 10,485,760 f
    short* Hall_b   = (short*)(s2 + (size_t)10485760);           // 2,621,440 s
    short* Wout_b   = (short*)(s2 + (size_t)10485760 + 1310720); // 10,354,688 s (padded)
    short* Wih_b    = Wout_b + (size_t)VPAD * HD;                // 4,194,304 s
    short* Whh_b    = Wih_b  + (size_t)G4 * HD;                  // 4,194,304 s
    short* Wini_h_b = Whh_b  + (size_t)G4 * HD;                  //   524,288 s
    short* Wini_c_b = Wini_h_b + (size_t)HD * DV;                //   524,288 s

    // ws small scratch
    char* w = (char*)d_ws;
    size_t off = 0;
    auto alloc = [&](size_t bytes) { void* p = w + off; off = (off + bytes + 255) & ~255UL; return p; };
    float* attv   = (float*)alloc((size_t)B * NLOC * 4);
    float* alpha  = (float*)alloc((size_t)B * NLOC * 4);
    float* gctx   = (float*)alloc((size_t)B * G4 * 4);
    float* h0f    = (float*)alloc((size_t)B * HD * 4);
    float* cbuf   = (float*)alloc((size_t)B * HD * 4);
    float* hW     = (float*)alloc((size_t)B * G4 * 4);
    short* fmean_b= (short*)alloc((size_t)B * DV * 2);
    short* ctx_b  = (short*)alloc((size_t)B * DV * 2);
    short* h_bf   = (short*)alloc((size_t)B * HD * 2);
    short* emb_b  = (short*)alloc((size_t)TT * B * EMB * 2);

    // ---- weight conversions (one-time per launch) ----
    f2bf_pad_kernel<<<((size_t)VPAD * HD + 255) / 256, 256, 0, stream>>>(
        W_out, Wout_b, (size_t)VV * HD, (size_t)VPAD * HD);
    f2bf_pad_kernel<<<((size_t)G4 * HD + 255) / 256, 256, 0, stream>>>(
        W_ih, Wih_b, (size_t)G4 * HD, (size_t)G4 * HD);
    f2bf_pad_kernel<<<((size_t)G4 * HD + 255) / 256, 256, 0, stream>>>(
        W_hh, Whh_b, (size_t)G4 * HD, (size_t)G4 * HD);
    f2bf_pad_kernel<<<((size_t)HD * DV + 255) / 256, 256, 0, stream>>>(
        W_init_h, Wini_h_b, (size_t)HD * DV, (size_t)HD * DV);
    f2bf_pad_kernel<<<((size_t)HD * DV + 255) / 256, 256, 0, stream>>>(
        W_init_c, Wini_c_b, (size_t)HD * DV, (size_t)HD * DV);

    // ---- phase 1: time-parallel ----
    fmean_kernel<<<(B * DV + 255) / 256, 256, 0, stream>>>(features, fmean_b);
    attv_kernel<<<B * NLOC, 64, 0, stream>>>(features, W_attn_v, b_attn_v, attv);
    alpha_kernel<<<B, 256, 0, stream>>>(attv, alpha);
    ctx_kernel<<<(B * DV + 255) / 256, 256, 0, stream>>>(features, alpha, ctx_b);
    emb_gather_kernel<<<((size_t)TT * B * EMB + 255) / 256, 256, 0, stream>>>(captions, embed_table, emb_b);

    // h0 / c0: [128 x 1024] = fmean_b[128x512] @ Wini^T
    gemm_bf16<32, 4, 1><<<dim3(HD / 32, 1), 256, 0, stream>>>(
        fmean_b, Wini_h_b, h0f, nullptr, nullptr, B, HD, DV, DV, DV, HD);
    gemm_bf16<32, 4, 1><<<dim3(HD / 32, 1), 256, 0, stream>>>(
        fmean_b, Wini_c_b, cbuf, nullptr, nullptr, B, HD, DV, DV, DV, HD);
    hcvt_kernel<<<(B * HD + 255) / 256, 256, 0, stream>>>(h0f, h_bf);

    // gctx = ctx @ W_ih[:, :512]^T + b_ih + b_hh
    gemm_bf16<32, 4, 1><<<dim3(G4 / 32, 1), 256, 0, stream>>>(
        ctx_b, Wih_b, gctx, b_ih, b_hh, B, G4, DV, DV, HD, G4);
    // gate_pre = emb @ W_ih[:, 512:]^T  (all T at once)
    gemm_bf16<128, 2, 2><<<dim3(G4 / 128, TT * B / 128), 256, 0, stream>>>(
        emb_b, Wih_b + DV, gate_pre, nullptr, nullptr, TT * B, G4, EMB, EMB, HD, G4);

    // ---- phase 2: recurrence ----
    for (int t = 0; t < TT; ++t) {
        gemm_bf16<32, 4, 1><<<dim3(G4 / 32, 1), 256, 0, stream>>>(
            h_bf, Whh_b, hW, nullptr, nullptr, B, G4, HD, HD, HD, G4);
        lstm_kernel<<<(B * HD + 255) / 256, 256, 0, stream>>>(
            hW, gate_pre + (size_t)t * B * G4, gctx, cbuf, h_bf, Hall_b + (size_t)t * B * HD);
    }

    // ---- phase 3: words = Hall @ W_out^T + b_out ----
    gemm_bf16<128, 2, 2><<<dim3(VPAD / 128, TT * B / 128), 256, 0, stream>>>(
        Hall_b, Wout_b, words, b_out, nullptr, TT * B, VV, HD, HD, HD, VV);
    softmax_kernel<<<TT * B, 512, 0, stream>>>(words, s2);
}

// Round 6
// 678.265 us; speedup vs baseline: 7.2390x; 1.0140x over previous
//
#include <hip/hip_runtime.h>
#include <math.h>

#define B    128
#define NLOC 196
#define DV   512
#define EMB  512
#define HD   1024
#define VV   10000
#define TT   20
#define G4   4096   // 4*HD
#define VPAD 10112  // 79*128
#define BH   (B*HD)

typedef short bf16x8 __attribute__((ext_vector_type(8)));
typedef float f32x4  __attribute__((ext_vector_type(4)));

__device__ __forceinline__ unsigned short f2bf(float x) {
    unsigned u = __builtin_bit_cast(unsigned, x);
    unsigned r = (u + 0x7fffu + ((u >> 16) & 1u)) >> 16;
    return (unsigned short)r;
}

__device__ __forceinline__ void gload_lds16(const void* g, void* lds) {
    __builtin_amdgcn_global_load_lds(
        (const __attribute__((address_space(1))) void*)g,
        (__attribute__((address_space(3))) void*)lds, 16, 0, 0);
}

// ---------------- small kernels ----------------

__global__ void fmean_kernel(const float* __restrict__ feat, short* __restrict__ fmean_b) {
    int idx = blockIdx.x * blockDim.x + threadIdx.x;   // B*DV
    if (idx >= B * DV) return;
    int b = idx / DV, d = idx % DV;
    const float* p = feat + (size_t)b * NLOC * DV + d;
    float s = 0.f;
    for (int n = 0; n < NLOC; ++n) s += p[(size_t)n * DV];
    fmean_b[idx] = (short)f2bf(s * (1.0f / NLOC));
}

__global__ void attv_kernel(const float* __restrict__ feat, const float* __restrict__ wv,
                            const float* __restrict__ bv, float* __restrict__ attv) {
    int row  = blockIdx.x;         // B*NLOC
    int lane = threadIdx.x;        // 64
    const float* p = feat + (size_t)row * DV;
    float s = 0.f;
    for (int k = lane; k < DV; k += 64) s += p[k] * wv[k];
    for (int off = 32; off > 0; off >>= 1) s += __shfl_down(s, off);
    if (lane == 0) attv[row] = s + bv[0];
}

__global__ void alpha_kernel(const float* __restrict__ attv, float* __restrict__ alpha) {
    int b   = blockIdx.x;          // B
    int tid = threadIdx.x;         // 256
    __shared__ float red[256];
    float v = (tid < NLOC) ? attv[b * NLOC + tid] : -1e30f;
    red[tid] = v; __syncthreads();
    for (int s = 128; s > 0; s >>= 1) { if (tid < s) red[tid] = fmaxf(red[tid], red[tid + s]); __syncthreads(); }
    float m = red[0]; __syncthreads();
    float e = (tid < NLOC) ? expf(v - m) : 0.f;
    red[tid] = e; __syncthreads();
    for (int s = 128; s > 0; s >>= 1) { if (tid < s) red[tid] += red[tid + s]; __syncthreads(); }
    float sum = red[0];
    if (tid < NLOC) alpha[b * NLOC + tid] = e / sum;
}

__global__ void ctx_kernel(const float* __restrict__ feat, const float* __restrict__ alpha,
                           short* __restrict__ ctx_b) {
    int idx = blockIdx.x * blockDim.x + threadIdx.x;   // B*DV
    if (idx >= B * DV) return;
    int b = idx / DV, d = idx % DV;
    const float* p = feat + (size_t)b * NLOC * DV + d;
    const float* a = alpha + b * NLOC;
    float s = 0.f;
    for (int n = 0; n < NLOC; ++n) s += a[n] * p[(size_t)n * DV];
    ctx_b[idx] = (short)f2bf(s);
}

__global__ void emb_gather_kernel(const int* __restrict__ captions, const float* __restrict__ table,
                                  short* __restrict__ emb_b) {
    size_t idx = (size_t)blockIdx.x * blockDim.x + threadIdx.x;   // T*B*EMB
    if (idx >= (size_t)TT * B * EMB) return;
    int k = (int)(idx % EMB);
    int r = (int)(idx / EMB);      // r = t*B + b
    int t = r / B, b = r % B;
    int cap = captions[b * TT + t];
    emb_b[idx] = (short)f2bf(table[(size_t)cap * EMB + k]);
}

__global__ void f2bf_pad_kernel(const float* __restrict__ in, short* __restrict__ out,
                                size_t n, size_t npad) {
    size_t i = (size_t)blockIdx.x * blockDim.x + threadIdx.x;
    if (i >= npad) return;
    out[i] = (i < n) ? (short)f2bf(in[i]) : (short)0;
}

__global__ void hcvt_kernel(const float* __restrict__ h, short* __restrict__ h_bf) {
    int idx = blockIdx.x * blockDim.x + threadIdx.x;   // B*HD
    if (idx >= B * HD) return;
    h_bf[idx] = (short)f2bf(h[idx]);
}

// ---------------- bf16 MFMA GEMM (round-2 proven): C[M,N] = A[M,K] @ Bw[N,K]^T ----------------
template<int BN, int WR, int WC>
__global__ __launch_bounds__(256)
void gemm_bf16(const short* __restrict__ A, const short* __restrict__ Bw,
               float* __restrict__ C,
               const float* __restrict__ bias0, const float* __restrict__ bias1,
               int M, int N, int K, int lda, int ldb, int ldc) {
    constexpr int BM = 128;
    constexpr int BK = 32;
    constexpr int WM = BM / WR;
    constexpr int WN = BN / WC;
    constexpr int FM = WM / 16;
    constexpr int FN = WN / 16;
    __shared__ __align__(16) short As[BM * BK];
    __shared__ __align__(16) short Bs[BN * BK];
    const int tid  = threadIdx.x;
    const int wave = tid >> 6, lane = tid & 63;
    const int wr = wave / WC, wc = wave % WC;
    const int m0 = blockIdx.y * BM, n0 = blockIdx.x * BN;
    const int laneoff = lane * 16;   // byte offset within wave segment

    f32x4 acc[FM][FN] = {};

    for (int k0 = 0; k0 < K; k0 += BK) {
        #pragma unroll
        for (int r = 0; r < 2; ++r) {
            int o   = r * 4096 + wave * 1024 + laneoff;  // byte offset in As
            int row = o >> 6;                            // 64 B per row
            int col = (o & 63) >> 1;
            gload_lds16(A + (size_t)(m0 + row) * lda + k0 + col,
                        (char*)As + r * 4096 + wave * 1024);
        }
        constexpr int BBYTES = BN * BK * 2;
        if constexpr (BBYTES >= 4096) {
            #pragma unroll
            for (int r = 0; r < BBYTES / 4096; ++r) {
                int o   = r * 4096 + wave * 1024 + laneoff;
                int row = o >> 6;
                int col = (o & 63) >> 1;
                gload_lds16(Bw + (size_t)(n0 + row) * ldb + k0 + col,
                            (char*)Bs + r * 4096 + wave * 1024);
            }
        } else {
            constexpr int NW = BBYTES / 1024;   // waves participating
            if (wave < NW) {
                int o   = wave * 1024 + laneoff;
                int row = o >> 6;
                int col = (o & 63) >> 1;
                gload_lds16(Bw + (size_t)(n0 + row) * ldb + k0 + col,
                            (char*)Bs + wave * 1024);
            }
        }
        __syncthreads();

        bf16x8 a[FM], b[FN];
        const int kfr = (lane >> 4) * 8;
        #pragma unroll
        for (int i = 0; i < FM; ++i) {
            int row = wr * WM + i * 16 + (lane & 15);
            a[i] = *(const bf16x8*)&As[row * BK + kfr];
        }
        #pragma unroll
        for (int j = 0; j < FN; ++j) {
            int row = wc * WN + j * 16 + (lane & 15);
            b[j] = *(const bf16x8*)&Bs[row * BK + kfr];
        }
        #pragma unroll
        for (int i = 0; i < FM; ++i)
            #pragma unroll
            for (int j = 0; j < FN; ++j)
                acc[i][j] = __builtin_amdgcn_mfma_f32_16x16x32_bf16(a[i], b[j], acc[i][j], 0, 0, 0);
        __syncthreads();
    }

    #pragma unroll
    for (int i = 0; i < FM; ++i) {
        #pragma unroll
        for (int j = 0; j < FN; ++j) {
            int col = n0 + wc * WN + j * 16 + (lane & 15);
            if (col >= N) continue;
            float bv = (bias0 ? bias0[col] : 0.f) + (bias1 ? bias1[col] : 0.f);
            #pragma unroll
            for (int q = 0; q < 4; ++q) {
                int row = m0 + wr * WM + i * 16 + (lane >> 4) * 4 + q;
                if (row < M) C[(size_t)row * ldc + col] = acc[i][j][q] + bv;
            }
        }
    }
}

// ---------------- fused recurrence step (the ONLY delta vs the passing binary) ----------------
// grid (HD/16, B/16), 256 threads = 4 waves; wave index = gate (i,f,g,o).
// Each wave computes one 16x16 gate tile; K-loop over 1024 with register fragments
// loaded straight from global (H 256 KB + W_hh 8 MB -> L2-resident).
// Hprev/Hnext are disjoint ping-pong buffers in d_ws (no in-launch aliasing).
__global__ __launch_bounds__(256)
void lstm_step(const short* __restrict__ Hprev, const short* __restrict__ Whh,
               const float* __restrict__ pre_t, const float* __restrict__ gctx,
               float* __restrict__ cbuf, short* __restrict__ Hnext,
               short* __restrict__ Hall_t) {
    __shared__ float gsm[4][16][16];
    const int tid  = threadIdx.x;
    const int lane = tid & 63;
    const int g    = tid >> 6;                 // wave = gate
    const int u0   = blockIdx.x * 16;
    const int r0   = blockIdx.y * 16;
    const int arow = r0 + (lane & 15);                  // H row
    const int brow = g * HD + u0 + (lane & 15);         // W_hh row
    const int kch  = (lane >> 4) * 8;                   // k chunk within 32

    const short* Ap = Hprev + (size_t)arow * HD + kch;
    const short* Bp = Whh   + (size_t)brow * HD + kch;

    f32x4 acc = {};
    for (int ks = 0; ks < HD / 32; ++ks) {
        bf16x8 a = *(const bf16x8*)(Ap + ks * 32);
        bf16x8 b = *(const bf16x8*)(Bp + ks * 32);
        acc = __builtin_amdgcn_mfma_f32_16x16x32_bf16(a, b, acc, 0, 0, 0);
    }

    // C-layout: col = lane&15 (unit), row = (lane>>4)*4 + q
    #pragma unroll
    for (int q = 0; q < 4; ++q)
        gsm[g][(lane >> 4) * 4 + q][lane & 15] = acc[q];
    __syncthreads();

    // elementwise: one thread per (row, unit) of the 16x16 tile
    const int rr = tid >> 4, uu = tid & 15;
    const int r = r0 + rr, u = u0 + uu;
    size_t pb = (size_t)r * G4 + u;
    float gi = gsm[0][rr][uu] + pre_t[pb]          + gctx[pb];
    float gf = gsm[1][rr][uu] + pre_t[pb + HD]     + gctx[pb + HD];
    float gg = gsm[2][rr][uu] + pre_t[pb + 2 * HD] + gctx[pb + 2 * HD];
    float go = gsm[3][rr][uu] + pre_t[pb + 3 * HD] + gctx[pb + 3 * HD];
    float si = 1.f / (1.f + expf(-gi));
    float sf = 1.f / (1.f + expf(-gf));
    float so = 1.f / (1.f + expf(-go));
    float cn = sf * cbuf[(size_t)r * HD + u] + si * tanhf(gg);
    float hn = so * tanhf(cn);
    cbuf[(size_t)r * HD + u] = cn;
    short hb = (short)f2bf(hn);
    Hnext[(size_t)r * HD + u]  = hb;
    Hall_t[(size_t)r * HD + u] = hb;
}

// ---------------- fused log_softmax + softmax over V ----------------
__global__ void softmax_kernel(float* __restrict__ words_logout, float* __restrict__ smout) {
    int r = blockIdx.x;            // T*B rows
    int tid = threadIdx.x;         // 512
    float* row = words_logout + (size_t)r * VV;
    __shared__ float red[512];
    float m = -1e30f;
    for (int i = tid; i < VV; i += 512) m = fmaxf(m, row[i]);
    red[tid] = m; __syncthreads();
    for (int s = 256; s > 0; s >>= 1) { if (tid < s) red[tid] = fmaxf(red[tid], red[tid + s]); __syncthreads(); }
    m = red[0]; __syncthreads();
    float sum = 0.f;
    for (int i = tid; i < VV; i += 512) sum += expf(row[i] - m);
    red[tid] = sum; __syncthreads();
    for (int s = 256; s > 0; s >>= 1) { if (tid < s) red[tid] += red[tid + s]; __syncthreads(); }
    sum = red[0];
    float lz = logf(sum);
    for (int i = tid; i < VV; i += 512) {
        float x = row[i];
        float e = expf(x - m);
        smout[(size_t)r * VV + i] = e / sum;
        row[i] = x - m - lz;
    }
}

// ---------------- launch ----------------
extern "C" void kernel_launch(void* const* d_in, const int* in_sizes, int n_in,
                              void* d_out, int out_size, void* d_ws, size_t ws_size,
                              hipStream_t stream) {
    const float* features    = (const float*)d_in[0];
    const int*   captions    = (const int*)  d_in[1];
    const float* W_init_h    = (const float*)d_in[2];
    const float* W_init_c    = (const float*)d_in[3];
    const float* W_attn_v    = (const float*)d_in[4];
    const float* b_attn_v    = (const float*)d_in[5];
    // d_in[6], d_in[7] (W_attn_h, b_attn_h) dead: softmax shift-invariance.
    const float* embed_table = (const float*)d_in[8];
    const float* W_ih        = (const float*)d_in[9];
    const float* W_hh        = (const float*)d_in[10];
    const float* b_ih        = (const float*)d_in[11];
    const float* b_hh        = (const float*)d_in[12];
    const float* W_out       = (const float*)d_in[13];
    const float* b_out       = (const float*)d_in[14];

    float* out   = (float*)d_out;
    float* words = out;                        // first half (log_softmax in place)
    float* s2    = out + (size_t)TT * B * VV;  // second half: scratch until final softmax

    // second-half scratch — byte-identical layout to the last-passing binary
    float* gate_pre = s2;                                        // 10,485,760 f
    short* Hall_b   = (short*)(s2 + (size_t)10485760);           // TT x B*HD bf16
    short* Wout_b   = (short*)(s2 + (size_t)10485760 + 1310720); // VPAD*HD
    short* Wih_b    = Wout_b + (size_t)VPAD * HD;                // (as in passing binary)
    short* Whh_b    = Wih_b  + (size_t)G4 * HD;
    short* Wini_h_b = Whh_b  + (size_t)G4 * HD;
    short* Wini_c_b = Wini_h_b + (size_t)HD * DV;

    // ws small scratch
    char* w = (char*)d_ws;
    size_t off = 0;
    auto alloc = [&](size_t bytes) { void* p = w + off; off = (off + bytes + 255) & ~255UL; return p; };
    float* attv   = (float*)alloc((size_t)B * NLOC * 4);
    float* alpha  = (float*)alloc((size_t)B * NLOC * 4);
    float* gctx   = (float*)alloc((size_t)B * G4 * 4);
    float* h0f    = (float*)alloc((size_t)B * HD * 4);
    float* cbuf   = (float*)alloc((size_t)B * HD * 4);
    short* fmean_b= (short*)alloc((size_t)B * DV * 2);
    short* ctx_b  = (short*)alloc((size_t)B * DV * 2);
    short* h_ping = (short*)alloc((size_t)B * HD * 2);
    short* h_pong = (short*)alloc((size_t)B * HD * 2);
    short* emb_b  = (short*)alloc((size_t)TT * B * EMB * 2);

    // ---- weight conversions (identical to passing binary) ----
    f2bf_pad_kernel<<<((size_t)VPAD * HD + 255) / 256, 256, 0, stream>>>(
        W_out, Wout_b, (size_t)VV * HD, (size_t)VPAD * HD);
    f2bf_pad_kernel<<<((size_t)G4 * HD + 255) / 256, 256, 0, stream>>>(
        W_ih, Wih_b, (size_t)G4 * HD, (size_t)G4 * HD);
    f2bf_pad_kernel<<<((size_t)G4 * HD + 255) / 256, 256, 0, stream>>>(
        W_hh, Whh_b, (size_t)G4 * HD, (size_t)G4 * HD);
    f2bf_pad_kernel<<<((size_t)HD * DV + 255) / 256, 256, 0, stream>>>(
        W_init_h, Wini_h_b, (size_t)HD * DV, (size_t)HD * DV);
    f2bf_pad_kernel<<<((size_t)HD * DV + 255) / 256, 256, 0, stream>>>(
        W_init_c, Wini_c_b, (size_t)HD * DV, (size_t)HD * DV);

    // ---- phase 1: time-parallel (identical) ----
    fmean_kernel<<<(B * DV + 255) / 256, 256, 0, stream>>>(features, fmean_b);
    attv_kernel<<<B * NLOC, 64, 0, stream>>>(features, W_attn_v, b_attn_v, attv);
    alpha_kernel<<<B, 256, 0, stream>>>(attv, alpha);
    ctx_kernel<<<(B * DV + 255) / 256, 256, 0, stream>>>(features, alpha, ctx_b);
    emb_gather_kernel<<<((size_t)TT * B * EMB + 255) / 256, 256, 0, stream>>>(captions, embed_table, emb_b);

    // h0 / c0 (identical)
    gemm_bf16<32, 4, 1><<<dim3(HD / 32, 1), 256, 0, stream>>>(
        fmean_b, Wini_h_b, h0f, nullptr, nullptr, B, HD, DV, DV, DV, HD);
    gemm_bf16<32, 4, 1><<<dim3(HD / 32, 1), 256, 0, stream>>>(
        fmean_b, Wini_c_b, cbuf, nullptr, nullptr, B, HD, DV, DV, DV, HD);
    hcvt_kernel<<<(B * HD + 255) / 256, 256, 0, stream>>>(h0f, h_ping);

    // gctx / gate_pre (identical call-sites to passing binary)
    gemm_bf16<32, 4, 1><<<dim3(G4 / 32, 1), 256, 0, stream>>>(
        ctx_b, Wih_b, gctx, b_ih, b_hh, B, G4, DV, DV, HD, G4);
    gemm_bf16<128, 2, 2><<<dim3(G4 / 128, TT * B / 128), 256, 0, stream>>>(
        emb_b, Wih_b + DV, gate_pre, nullptr, nullptr, TT * B, G4, EMB, EMB, DV + EMB, G4);

    // ---- phase 2: fused recurrence (THE single delta) ----
    for (int t = 0; t < TT; ++t) {
        lstm_step<<<dim3(HD / 16, B / 16), 256, 0, stream>>>(
            (t & 1) ? h_pong : h_ping, Whh_b, gate_pre + (size_t)t * B * G4, gctx,
            cbuf, (t & 1) ? h_ping : h_pong, Hall_b + (size_t)t * BH);
    }

    // ---- phase 3: words = Hall @ W_out^T + b_out (identical) ----
    gemm_bf16<128, 2, 2><<<dim3(VPAD / 128, TT * B / 128), 256, 0, stream>>>(
        Hall_b, Wout_b, words, b_out, nullptr, TT * B, VV, HD, HD, HD, VV);
    softmax_kernel<<<TT * B, 512, 0, stream>>>(words, s2);
}

// Round 7
// 614.787 us; speedup vs baseline: 7.9864x; 1.1033x over previous
//
#include <hip/hip_runtime.h>
#include <math.h>

#define B    128
#define NLOC 196
#define DV   512
#define EMB  512
#define HD   1024
#define VV   10000
#define TT   20
#define G4   4096   // 4*HD
#define VPAD 10112  // 79*128
#define BH   (B*HD)

typedef short bf16x8 __attribute__((ext_vector_type(8)));
typedef float f32x4  __attribute__((ext_vector_type(4)));

__device__ __forceinline__ unsigned short f2bf(float x) {
    unsigned u = __builtin_bit_cast(unsigned, x);
    unsigned r = (u + 0x7fffu + ((u >> 16) & 1u)) >> 16;
    return (unsigned short)r;
}

__device__ __forceinline__ void gload_lds16(const void* g, void* lds) {
    __builtin_amdgcn_global_load_lds(
        (const __attribute__((address_space(1))) void*)g,
        (__attribute__((address_space(3))) void*)lds, 16, 0, 0);
}

// ---------------- small kernels ----------------

__global__ void fmean_kernel(const float* __restrict__ feat, short* __restrict__ fmean_b) {
    int idx = blockIdx.x * blockDim.x + threadIdx.x;   // B*DV
    if (idx >= B * DV) return;
    int b = idx / DV, d = idx % DV;
    const float* p = feat + (size_t)b * NLOC * DV + d;
    float s = 0.f;
    for (int n = 0; n < NLOC; ++n) s += p[(size_t)n * DV];
    fmean_b[idx] = (short)f2bf(s * (1.0f / NLOC));
}

__global__ void attv_kernel(const float* __restrict__ feat, const float* __restrict__ wv,
                            const float* __restrict__ bv, float* __restrict__ attv) {
    int row  = blockIdx.x;         // B*NLOC
    int lane = threadIdx.x;        // 64
    const float* p = feat + (size_t)row * DV;
    float s = 0.f;
    for (int k = lane; k < DV; k += 64) s += p[k] * wv[k];
    for (int off = 32; off > 0; off >>= 1) s += __shfl_down(s, off);
    if (lane == 0) attv[row] = s + bv[0];
}

__global__ void alpha_kernel(const float* __restrict__ attv, float* __restrict__ alpha) {
    int b   = blockIdx.x;          // B
    int tid = threadIdx.x;         // 256
    __shared__ float red[256];
    float v = (tid < NLOC) ? attv[b * NLOC + tid] : -1e30f;
    red[tid] = v; __syncthreads();
    for (int s = 128; s > 0; s >>= 1) { if (tid < s) red[tid] = fmaxf(red[tid], red[tid + s]); __syncthreads(); }
    float m = red[0]; __syncthreads();
    float e = (tid < NLOC) ? expf(v - m) : 0.f;
    red[tid] = e; __syncthreads();
    for (int s = 128; s > 0; s >>= 1) { if (tid < s) red[tid] += red[tid + s]; __syncthreads(); }
    float sum = red[0];
    if (tid < NLOC) alpha[b * NLOC + tid] = e / sum;
}

__global__ void ctx_kernel(const float* __restrict__ feat, const float* __restrict__ alpha,
                           short* __restrict__ ctx_b) {
    int idx = blockIdx.x * blockDim.x + threadIdx.x;   // B*DV
    if (idx >= B * DV) return;
    int b = idx / DV, d = idx % DV;
    const float* p = feat + (size_t)b * NLOC * DV + d;
    const float* a = alpha + b * NLOC;
    float s = 0.f;
    for (int n = 0; n < NLOC; ++n) s += a[n] * p[(size_t)n * DV];
    ctx_b[idx] = (short)f2bf(s);
}

__global__ void emb_gather_kernel(const int* __restrict__ captions, const float* __restrict__ table,
                                  short* __restrict__ emb_b) {
    size_t idx = (size_t)blockIdx.x * blockDim.x + threadIdx.x;   // T*B*EMB
    if (idx >= (size_t)TT * B * EMB) return;
    int k = (int)(idx % EMB);
    int r = (int)(idx / EMB);      // r = t*B + b
    int t = r / B, b = r % B;
    int cap = captions[b * TT + t];
    emb_b[idx] = (short)f2bf(table[(size_t)cap * EMB + k]);
}

__global__ void f2bf_pad_kernel(const float* __restrict__ in, short* __restrict__ out,
                                size_t n, size_t npad) {
    size_t i = (size_t)blockIdx.x * blockDim.x + threadIdx.x;
    if (i >= npad) return;
    out[i] = (i < n) ? (short)f2bf(in[i]) : (short)0;
}

// W_hh [4096][1024] -> gate-interleaved rows P = u*4 + g (same buffer size)
__global__ void whh_perm_kernel(const float* __restrict__ in, short* __restrict__ out) {
    size_t idx = (size_t)blockIdx.x * blockDim.x + threadIdx.x;   // G4*HD
    if (idx >= (size_t)G4 * HD) return;
    int k = (int)(idx & (HD - 1));
    int P = (int)(idx >> 10);
    int u = P >> 2, g = P & 3;
    out[idx] = (short)f2bf(in[(size_t)(g * HD + u) * HD + k]);
}

__global__ void hcvt_kernel(const float* __restrict__ h, short* __restrict__ h_bf) {
    int idx = blockIdx.x * blockDim.x + threadIdx.x;   // B*HD
    if (idx >= B * HD) return;
    h_bf[idx] = (short)f2bf(h[idx]);
}

// ---------------- bf16 MFMA GEMM (twice-proven): C[M,N] = A[M,K] @ Bw[N,K]^T ----------------
template<int BN, int WR, int WC>
__global__ __launch_bounds__(256)
void gemm_bf16(const short* __restrict__ A, const short* __restrict__ Bw,
               float* __restrict__ C,
               const float* __restrict__ bias0, const float* __restrict__ bias1,
               int M, int N, int K, int lda, int ldb, int ldc) {
    constexpr int BM = 128;
    constexpr int BK = 32;
    constexpr int WM = BM / WR;
    constexpr int WN = BN / WC;
    constexpr int FM = WM / 16;
    constexpr int FN = WN / 16;
    __shared__ __align__(16) short As[BM * BK];
    __shared__ __align__(16) short Bs[BN * BK];
    const int tid  = threadIdx.x;
    const int wave = tid >> 6, lane = tid & 63;
    const int wr = wave / WC, wc = wave % WC;
    const int m0 = blockIdx.y * BM, n0 = blockIdx.x * BN;
    const int laneoff = lane * 16;   // byte offset within wave segment

    f32x4 acc[FM][FN] = {};

    for (int k0 = 0; k0 < K; k0 += BK) {
        #pragma unroll
        for (int r = 0; r < 2; ++r) {
            int o   = r * 4096 + wave * 1024 + laneoff;  // byte offset in As
            int row = o >> 6;                            // 64 B per row
            int col = (o & 63) >> 1;
            gload_lds16(A + (size_t)(m0 + row) * lda + k0 + col,
                        (char*)As + r * 4096 + wave * 1024);
        }
        constexpr int BBYTES = BN * BK * 2;
        if constexpr (BBYTES >= 4096) {
            #pragma unroll
            for (int r = 0; r < BBYTES / 4096; ++r) {
                int o   = r * 4096 + wave * 1024 + laneoff;
                int row = o >> 6;
                int col = (o & 63) >> 1;
                gload_lds16(Bw + (size_t)(n0 + row) * ldb + k0 + col,
                            (char*)Bs + r * 4096 + wave * 1024);
            }
        } else {
            constexpr int NW = BBYTES / 1024;   // waves participating
            if (wave < NW) {
                int o   = wave * 1024 + laneoff;
                int row = o >> 6;
                int col = (o & 63) >> 1;
                gload_lds16(Bw + (size_t)(n0 + row) * ldb + k0 + col,
                            (char*)Bs + wave * 1024);
            }
        }
        __syncthreads();

        bf16x8 a[FM], b[FN];
        const int kfr = (lane >> 4) * 8;
        #pragma unroll
        for (int i = 0; i < FM; ++i) {
            int row = wr * WM + i * 16 + (lane & 15);
            a[i] = *(const bf16x8*)&As[row * BK + kfr];
        }
        #pragma unroll
        for (int j = 0; j < FN; ++j) {
            int row = wc * WN + j * 16 + (lane & 15);
            b[j] = *(const bf16x8*)&Bs[row * BK + kfr];
        }
        #pragma unroll
        for (int i = 0; i < FM; ++i)
            #pragma unroll
            for (int j = 0; j < FN; ++j)
                acc[i][j] = __builtin_amdgcn_mfma_f32_16x16x32_bf16(a[i], b[j], acc[i][j], 0, 0, 0);
        __syncthreads();
    }

    #pragma unroll
    for (int i = 0; i < FM; ++i) {
        #pragma unroll
        for (int j = 0; j < FN; ++j) {
            int col = n0 + wc * WN + j * 16 + (lane & 15);
            if (col >= N) continue;
            float bv = (bias0 ? bias0[col] : 0.f) + (bias1 ? bias1[col] : 0.f);
            #pragma unroll
            for (int q = 0; q < 4; ++q) {
                int row = m0 + wr * WM + i * 16 + (lane >> 4) * 4 + q;
                if (row < M) C[(size_t)row * ldc + col] = acc[i][j][q] + bv;
            }
        }
    }
}

// ---------------- fused recurrence step v2: LDS-tiled GEMM + LSTM elementwise ----------------
// grid (HD/8 = 128, B/64 = 2), 256 threads = 4 waves (wr = wave>>1, wc = wave&1).
// Block: 64 batch rows x 32 P-rows (8 units x 4 gates, P = u*4+g contiguous in Whh_p).
// Staging identical idiom to gemm_bf16: BK=32, 64B LDS rows, wave-uniform LDS dest.
__global__ __launch_bounds__(256)
void lstm_step2(const short* __restrict__ Hprev, const short* __restrict__ Whh_p,
                const float* __restrict__ pre_t, const float* __restrict__ gctx,
                float* __restrict__ cbuf, short* __restrict__ Hnext,
                short* __restrict__ Hall_t) {
    __shared__ __align__(16) short As[64 * 32];   // 4 KB
    __shared__ __align__(16) short Bs[32 * 32];   // 2 KB
    __shared__ float gsm[4][64][8];               // 8 KB
    const int tid  = threadIdx.x;
    const int lane = tid & 63, wave = tid >> 6;
    const int wr = wave >> 1, wc = wave & 1;
    const int n0 = blockIdx.x * 32;               // P base (unit block u0 = blockIdx.x*8)
    const int m0 = blockIdx.y * 64;               // batch base
    const int srow = tid >> 2;                    // 0..63 (64 B per LDS row)
    const int scol = (tid & 3) * 8;
    const short* Abase = Hprev + (size_t)(m0 + srow) * HD + scol;
    const short* Bbase = Whh_p + (size_t)(n0 + srow) * HD + scol;   // used by waves 0,1 (srow<32)

    f32x4 acc[2] = {};

    for (int ks = 0; ks < HD / 32; ++ks) {
        const int k0 = ks * 32;
        gload_lds16(Abase + k0, (char*)As + wave * 1024);
        if (wave < 2) gload_lds16(Bbase + k0, (char*)Bs + wave * 1024);
        __syncthreads();
        const int kfr = (lane >> 4) * 8;
        bf16x8 bfrag = *(const bf16x8*)&Bs[(wc * 16 + (lane & 15)) * 32 + kfr];
        #pragma unroll
        for (int i = 0; i < 2; ++i) {
            bf16x8 afrag = *(const bf16x8*)&As[(wr * 32 + i * 16 + (lane & 15)) * 32 + kfr];
            acc[i] = __builtin_amdgcn_mfma_f32_16x16x32_bf16(afrag, bfrag, acc[i], 0, 0, 0);
        }
        __syncthreads();
    }

    // scatter gate values: lane's col p = wc*16+(lane&15) -> unit uu = p>>2, gate g = p&3
    const int p  = wc * 16 + (lane & 15);
    const int uu = p >> 2, g = p & 3;
    #pragma unroll
    for (int i = 0; i < 2; ++i)
        #pragma unroll
        for (int q = 0; q < 4; ++q)
            gsm[g][wr * 32 + i * 16 + (lane >> 4) * 4 + q][uu] = acc[i][q];
    __syncthreads();

    // fused LSTM elementwise: 64 rows x 8 units = 512 elems, 2 per thread
    #pragma unroll
    for (int s = 0; s < 2; ++s) {
        int idx = tid + s * 256;
        int m = idx >> 3, u8 = idx & 7;
        int r = m0 + m, u = blockIdx.x * 8 + u8;
        size_t pb = (size_t)r * G4 + u;
        float gi = gsm[0][m][u8] + pre_t[pb]          + gctx[pb];
        float gf = gsm[1][m][u8] + pre_t[pb + HD]     + gctx[pb + HD];
        float gg = gsm[2][m][u8] + pre_t[pb + 2 * HD] + gctx[pb + 2 * HD];
        float go = gsm[3][m][u8] + pre_t[pb + 3 * HD] + gctx[pb + 3 * HD];
        float si = 1.f / (1.f + expf(-gi));
        float sf = 1.f / (1.f + expf(-gf));
        float so = 1.f / (1.f + expf(-go));
        float cn = sf * cbuf[(size_t)r * HD + u] + si * tanhf(gg);
        float hn = so * tanhf(cn);
        cbuf[(size_t)r * HD + u] = cn;
        short hb = (short)f2bf(hn);
        Hnext[(size_t)r * HD + u]  = hb;
        Hall_t[(size_t)r * HD + u] = hb;
    }
}

// ---------------- fused log_softmax + softmax over V ----------------
__global__ void softmax_kernel(float* __restrict__ words_logout, float* __restrict__ smout) {
    int r = blockIdx.x;            // T*B rows
    int tid = threadIdx.x;         // 512
    float* row = words_logout + (size_t)r * VV;
    __shared__ float red[512];
    float m = -1e30f;
    for (int i = tid; i < VV; i += 512) m = fmaxf(m, row[i]);
    red[tid] = m; __syncthreads();
    for (int s = 256; s > 0; s >>= 1) { if (tid < s) red[tid] = fmaxf(red[tid], red[tid + s]); __syncthreads(); }
    m = red[0]; __syncthreads();
    float sum = 0.f;
    for (int i = tid; i < VV; i += 512) sum += expf(row[i] - m);
    red[tid] = sum; __syncthreads();
    for (int s = 256; s > 0; s >>= 1) { if (tid < s) red[tid] += red[tid + s]; __syncthreads(); }
    sum = red[0];
    float lz = logf(sum);
    for (int i = tid; i < VV; i += 512) {
        float x = row[i];
        float e = expf(x - m);
        smout[(size_t)r * VV + i] = e / sum;
        row[i] = x - m - lz;
    }
}

// ---------------- launch ----------------
extern "C" void kernel_launch(void* const* d_in, const int* in_sizes, int n_in,
                              void* d_out, int out_size, void* d_ws, size_t ws_size,
                              hipStream_t stream) {
    const float* features    = (const float*)d_in[0];
    const int*   captions    = (const int*)  d_in[1];
    const float* W_init_h    = (const float*)d_in[2];
    const float* W_init_c    = (const float*)d_in[3];
    const float* W_attn_v    = (const float*)d_in[4];
    const float* b_attn_v    = (const float*)d_in[5];
    // d_in[6], d_in[7] (W_attn_h, b_attn_h) dead: softmax shift-invariance.
    const float* embed_table = (const float*)d_in[8];
    const float* W_ih        = (const float*)d_in[9];
    const float* W_hh        = (const float*)d_in[10];
    const float* b_ih        = (const float*)d_in[11];
    const float* b_hh        = (const float*)d_in[12];
    const float* W_out       = (const float*)d_in[13];
    const float* b_out       = (const float*)d_in[14];

    float* out   = (float*)d_out;
    float* words = out;                        // first half (log_softmax in place)
    float* s2    = out + (size_t)TT * B * VV;  // second half: scratch until final softmax

    // second-half scratch — byte-identical layout to the passing binary (FROZEN)
    float* gate_pre = s2;                                        // 10,485,760 f
    short* Hall_b   = (short*)(s2 + (size_t)10485760);           // TT x B*HD bf16
    short* Wout_b   = (short*)(s2 + (size_t)10485760 + 1310720); // VPAD*HD
    short* Wih_b    = Wout_b + (size_t)VPAD * HD;
    short* Whh_b    = Wih_b  + (size_t)G4 * HD;                  // now holds PERMUTED W_hh
    short* Wini_h_b = Whh_b  + (size_t)G4 * HD;
    short* Wini_c_b = Wini_h_b + (size_t)HD * DV;

    // ws small scratch
    char* w = (char*)d_ws;
    size_t off = 0;
    auto alloc = [&](size_t bytes) { void* p = w + off; off = (off + bytes + 255) & ~255UL; return p; };
    float* attv   = (float*)alloc((size_t)B * NLOC * 4);
    float* alpha  = (float*)alloc((size_t)B * NLOC * 4);
    float* gctx   = (float*)alloc((size_t)B * G4 * 4);
    float* h0f    = (float*)alloc((size_t)B * HD * 4);
    float* cbuf   = (float*)alloc((size_t)B * HD * 4);
    short* fmean_b= (short*)alloc((size_t)B * DV * 2);
    short* ctx_b  = (short*)alloc((size_t)B * DV * 2);
    short* h_ping = (short*)alloc((size_t)B * HD * 2);
    short* h_pong = (short*)alloc((size_t)B * HD * 2);
    short* emb_b  = (short*)alloc((size_t)TT * B * EMB * 2);

    // ---- weight conversions (identical except W_hh permuted in place of row-major) ----
    f2bf_pad_kernel<<<((size_t)VPAD * HD + 255) / 256, 256, 0, stream>>>(
        W_out, Wout_b, (size_t)VV * HD, (size_t)VPAD * HD);
    f2bf_pad_kernel<<<((size_t)G4 * HD + 255) / 256, 256, 0, stream>>>(
        W_ih, Wih_b, (size_t)G4 * HD, (size_t)G4 * HD);
    whh_perm_kernel<<<((size_t)G4 * HD + 255) / 256, 256, 0, stream>>>(W_hh, Whh_b);
    f2bf_pad_kernel<<<((size_t)HD * DV + 255) / 256, 256, 0, stream>>>(
        W_init_h, Wini_h_b, (size_t)HD * DV, (size_t)HD * DV);
    f2bf_pad_kernel<<<((size_t)HD * DV + 255) / 256, 256, 0, stream>>>(
        W_init_c, Wini_c_b, (size_t)HD * DV, (size_t)HD * DV);

    // ---- phase 1: time-parallel (identical) ----
    fmean_kernel<<<(B * DV + 255) / 256, 256, 0, stream>>>(features, fmean_b);
    attv_kernel<<<B * NLOC, 64, 0, stream>>>(features, W_attn_v, b_attn_v, attv);
    alpha_kernel<<<B, 256, 0, stream>>>(attv, alpha);
    ctx_kernel<<<(B * DV + 255) / 256, 256, 0, stream>>>(features, alpha, ctx_b);
    emb_gather_kernel<<<((size_t)TT * B * EMB + 255) / 256, 256, 0, stream>>>(captions, embed_table, emb_b);

    // h0 / c0 (identical)
    gemm_bf16<32, 4, 1><<<dim3(HD / 32, 1), 256, 0, stream>>>(
        fmean_b, Wini_h_b, h0f, nullptr, nullptr, B, HD, DV, DV, DV, HD);
    gemm_bf16<32, 4, 1><<<dim3(HD / 32, 1), 256, 0, stream>>>(
        fmean_b, Wini_c_b, cbuf, nullptr, nullptr, B, HD, DV, DV, DV, HD);
    hcvt_kernel<<<(B * HD + 255) / 256, 256, 0, stream>>>(h0f, h_ping);

    // gctx / gate_pre (identical call-sites)
    gemm_bf16<32, 4, 1><<<dim3(G4 / 32, 1), 256, 0, stream>>>(
        ctx_b, Wih_b, gctx, b_ih, b_hh, B, G4, DV, DV, HD, G4);
    gemm_bf16<128, 2, 2><<<dim3(G4 / 128, TT * B / 128), 256, 0, stream>>>(
        emb_b, Wih_b + DV, gate_pre, nullptr, nullptr, TT * B, G4, EMB, EMB, DV + EMB, G4);

    // ---- phase 2: fused recurrence (rewritten step kernel — THE delta) ----
    for (int t = 0; t < TT; ++t) {
        lstm_step2<<<dim3(HD / 8, B / 64), 256, 0, stream>>>(
            (t & 1) ? h_pong : h_ping, Whh_b, gate_pre + (size_t)t * B * G4, gctx,
            cbuf, (t & 1) ? h_ping : h_pong, Hall_b + (size_t)t * BH);
    }

    // ---- phase 3: words = Hall @ W_out^T + b_out (identical) ----
    gemm_bf16<128, 2, 2><<<dim3(VPAD / 128, TT * B / 128), 256, 0, stream>>>(
        Hall_b, Wout_b, words, b_out, nullptr, TT * B, VV, HD, HD, HD, VV);
    softmax_kernel<<<TT * B, 512, 0, stream>>>(words, s2);
}

// Round 8
// 555.021 us; speedup vs baseline: 8.8464x; 1.1077x over previous
//
#include <hip/hip_runtime.h>
#include <math.h>

#define B    128
#define NLOC 196
#define DV   512
#define EMB  512
#define HD   1024
#define VV   10000
#define TT   20
#define G4   4096   // 4*HD
#define VPAD 10112  // 79*128
#define BH   (B*HD)

typedef short bf16x8 __attribute__((ext_vector_type(8)));
typedef float f32x4  __attribute__((ext_vector_type(4)));

__device__ __forceinline__ unsigned short f2bf(float x) {
    unsigned u = __builtin_bit_cast(unsigned, x);
    unsigned r = (u + 0x7fffu + ((u >> 16) & 1u)) >> 16;
    return (unsigned short)r;
}

__device__ __forceinline__ void gload_lds16(const void* g, void* lds) {
    __builtin_amdgcn_global_load_lds(
        (const __attribute__((address_space(1))) void*)g,
        (__attribute__((address_space(3))) void*)lds, 16, 0, 0);
}

// ---------------- small kernels ----------------

__global__ void fmean_kernel(const float* __restrict__ feat, short* __restrict__ fmean_b) {
    int idx = blockIdx.x * blockDim.x + threadIdx.x;   // B*DV
    if (idx >= B * DV) return;
    int b = idx / DV, d = idx % DV;
    const float* p = feat + (size_t)b * NLOC * DV + d;
    float s = 0.f;
    for (int n = 0; n < NLOC; ++n) s += p[(size_t)n * DV];
    fmean_b[idx] = (short)f2bf(s * (1.0f / NLOC));
}

__global__ void attv_kernel(const float* __restrict__ feat, const float* __restrict__ wv,
                            const float* __restrict__ bv, float* __restrict__ attv) {
    int row  = blockIdx.x;         // B*NLOC
    int lane = threadIdx.x;        // 64
    const float* p = feat + (size_t)row * DV;
    float s = 0.f;
    for (int k = lane; k < DV; k += 64) s += p[k] * wv[k];
    for (int off = 32; off > 0; off >>= 1) s += __shfl_down(s, off);
    if (lane == 0) attv[row] = s + bv[0];
}

__global__ void alpha_kernel(const float* __restrict__ attv, float* __restrict__ alpha) {
    int b   = blockIdx.x;          // B
    int tid = threadIdx.x;         // 256
    __shared__ float red[256];
    float v = (tid < NLOC) ? attv[b * NLOC + tid] : -1e30f;
    red[tid] = v; __syncthreads();
    for (int s = 128; s > 0; s >>= 1) { if (tid < s) red[tid] = fmaxf(red[tid], red[tid + s]); __syncthreads(); }
    float m = red[0]; __syncthreads();
    float e = (tid < NLOC) ? expf(v - m) : 0.f;
    red[tid] = e; __syncthreads();
    for (int s = 128; s > 0; s >>= 1) { if (tid < s) red[tid] += red[tid + s]; __syncthreads(); }
    float sum = red[0];
    if (tid < NLOC) alpha[b * NLOC + tid] = e / sum;
}

__global__ void ctx_kernel(const float* __restrict__ feat, const float* __restrict__ alpha,
                           short* __restrict__ ctx_b) {
    int idx = blockIdx.x * blockDim.x + threadIdx.x;   // B*DV
    if (idx >= B * DV) return;
    int b = idx / DV, d = idx % DV;
    const float* p = feat + (size_t)b * NLOC * DV + d;
    const float* a = alpha + b * NLOC;
    float s = 0.f;
    for (int n = 0; n < NLOC; ++n) s += a[n] * p[(size_t)n * DV];
    ctx_b[idx] = (short)f2bf(s);
}

__global__ void emb_gather_kernel(const int* __restrict__ captions, const float* __restrict__ table,
                                  short* __restrict__ emb_b) {
    size_t idx = (size_t)blockIdx.x * blockDim.x + threadIdx.x;   // T*B*EMB
    if (idx >= (size_t)TT * B * EMB) return;
    int k = (int)(idx % EMB);
    int r = (int)(idx / EMB);      // r = t*B + b
    int t = r / B, b = r % B;
    int cap = captions[b * TT + t];
    emb_b[idx] = (short)f2bf(table[(size_t)cap * EMB + k]);
}

__global__ void f2bf_pad_kernel(const float* __restrict__ in, short* __restrict__ out,
                                size_t n, size_t npad) {
    size_t i = (size_t)blockIdx.x * blockDim.x + threadIdx.x;
    if (i >= npad) return;
    out[i] = (i < n) ? (short)f2bf(in[i]) : (short)0;
}

// W_hh [4096][1024] -> gate-interleaved rows P = u*4 + g (same buffer size)
__global__ void whh_perm_kernel(const float* __restrict__ in, short* __restrict__ out) {
    size_t idx = (size_t)blockIdx.x * blockDim.x + threadIdx.x;   // G4*HD
    if (idx >= (size_t)G4 * HD) return;
    int k = (int)(idx & (HD - 1));
    int P = (int)(idx >> 10);
    int u = P >> 2, g = P & 3;
    out[idx] = (short)f2bf(in[(size_t)(g * HD + u) * HD + k]);
}

__global__ void hcvt_kernel(const float* __restrict__ h, short* __restrict__ h_bf) {
    int idx = blockIdx.x * blockDim.x + threadIdx.x;   // B*HD
    if (idx >= B * HD) return;
    h_bf[idx] = (short)f2bf(h[idx]);
}

// ---------------- bf16 MFMA GEMM (thrice-proven, UNTOUCHED): C = A @ Bw^T ----------------
template<int BN, int WR, int WC>
__global__ __launch_bounds__(256)
void gemm_bf16(const short* __restrict__ A, const short* __restrict__ Bw,
               float* __restrict__ C,
               const float* __restrict__ bias0, const float* __restrict__ bias1,
               int M, int N, int K, int lda, int ldb, int ldc) {
    constexpr int BM = 128;
    constexpr int BK = 32;
    constexpr int WM = BM / WR;
    constexpr int WN = BN / WC;
    constexpr int FM = WM / 16;
    constexpr int FN = WN / 16;
    __shared__ __align__(16) short As[BM * BK];
    __shared__ __align__(16) short Bs[BN * BK];
    const int tid  = threadIdx.x;
    const int wave = tid >> 6, lane = tid & 63;
    const int wr = wave / WC, wc = wave % WC;
    const int m0 = blockIdx.y * BM, n0 = blockIdx.x * BN;
    const int laneoff = lane * 16;   // byte offset within wave segment

    f32x4 acc[FM][FN] = {};

    for (int k0 = 0; k0 < K; k0 += BK) {
        #pragma unroll
        for (int r = 0; r < 2; ++r) {
            int o   = r * 4096 + wave * 1024 + laneoff;  // byte offset in As
            int row = o >> 6;                            // 64 B per row
            int col = (o & 63) >> 1;
            gload_lds16(A + (size_t)(m0 + row) * lda + k0 + col,
                        (char*)As + r * 4096 + wave * 1024);
        }
        constexpr int BBYTES = BN * BK * 2;
        if constexpr (BBYTES >= 4096) {
            #pragma unroll
            for (int r = 0; r < BBYTES / 4096; ++r) {
                int o   = r * 4096 + wave * 1024 + laneoff;
                int row = o >> 6;
                int col = (o & 63) >> 1;
                gload_lds16(Bw + (size_t)(n0 + row) * ldb + k0 + col,
                            (char*)Bs + r * 4096 + wave * 1024);
            }
        } else {
            constexpr int NW = BBYTES / 1024;   // waves participating
            if (wave < NW) {
                int o   = wave * 1024 + laneoff;
                int row = o >> 6;
                int col = (o & 63) >> 1;
                gload_lds16(Bw + (size_t)(n0 + row) * ldb + k0 + col,
                            (char*)Bs + wave * 1024);
            }
        }
        __syncthreads();

        bf16x8 a[FM], b[FN];
        const int kfr = (lane >> 4) * 8;
        #pragma unroll
        for (int i = 0; i < FM; ++i) {
            int row = wr * WM + i * 16 + (lane & 15);
            a[i] = *(const bf16x8*)&As[row * BK + kfr];
        }
        #pragma unroll
        for (int j = 0; j < FN; ++j) {
            int row = wc * WN + j * 16 + (lane & 15);
            b[j] = *(const bf16x8*)&Bs[row * BK + kfr];
        }
        #pragma unroll
        for (int i = 0; i < FM; ++i)
            #pragma unroll
            for (int j = 0; j < FN; ++j)
                acc[i][j] = __builtin_amdgcn_mfma_f32_16x16x32_bf16(a[i], b[j], acc[i][j], 0, 0, 0);
        __syncthreads();
    }

    #pragma unroll
    for (int i = 0; i < FM; ++i) {
        #pragma unroll
        for (int j = 0; j < FN; ++j) {
            int col = n0 + wc * WN + j * 16 + (lane & 15);
            if (col >= N) continue;
            float bv = (bias0 ? bias0[col] : 0.f) + (bias1 ? bias1[col] : 0.f);
            #pragma unroll
            for (int q = 0; q < 4; ++q) {
                int row = m0 + wr * WM + i * 16 + (lane >> 4) * 4 + q;
                if (row < M) C[(size_t)row * ldc + col] = acc[i][j][q] + bv;
            }
        }
    }
}

// ---------------- fused recurrence step v3: dbuf pipeline + swizzle + 512 blocks ----------------
// grid (HD/8 = 128, B/32 = 4) = 512 blocks (2/CU), 256 threads = 4 waves (wr=wave>>1, wc=wave&1).
// Block: 32 batch rows x 32 P-rows (8 units x 4 gates, P = u*4+g in Whh_p).
// One barrier per k-iter: stage buf[cur^1] for ks+1, compute buf[cur], sync.
// Bank-conflict swizzle (rule 21, both sides): LDS granule s of row r holds global
// granule s ^ ((r>>1)&3); LDS stays linear for global_load_lds (wave-uniform base).
__global__ __launch_bounds__(256)
void lstm_step3(const short* __restrict__ Hprev, const short* __restrict__ Whh_p,
                const float* __restrict__ pre_t, const float* __restrict__ gctx,
                float* __restrict__ cbuf, short* __restrict__ Hnext,
                short* __restrict__ Hall_t) {
    __shared__ __align__(16) short As[2][32 * 32];   // 2 KB each
    __shared__ __align__(16) short Bs[2][32 * 32];
    __shared__ float gsm[4][32][8];                  // 4 KB
    const int tid  = threadIdx.x;
    const int lane = tid & 63, wave = tid >> 6;
    const int wr = wave >> 1, wc = wave & 1;
    const int n0 = blockIdx.x * 32;                  // P base (units blockIdx.x*8..+7)
    const int m0 = blockIdx.y * 32;                  // batch base

    // staging: threads 0-127 -> A-tile (2 KB), threads 128-255 -> B-tile (2 KB)
    const bool sA = tid < 128;
    const int  st = sA ? tid : tid - 128;
    const int  srow = st >> 2;                       // 0..31 (64 B LDS rows)
    const int  sgr  = st & 3;                        // LDS granule 0..3
    const int  scol = (sgr ^ ((srow >> 1) & 3)) * 8; // swizzled global elem col
    const short* gsrc = sA ? (Hprev + (size_t)(m0 + srow) * HD + scol)
                           : (Whh_p + (size_t)(n0 + srow) * HD + scol);
    const int ldsoff = (wave & 1) * 1024;            // wave-uniform 1 KB chunk

    f32x4 acc = {};

    // prologue: stage ks=0 into buf 0
    gload_lds16(gsrc, (char*)(sA ? As[0] : Bs[0]) + ldsoff);
    __syncthreads();

    int cur = 0;
    for (int ks = 0; ks < HD / 32; ++ks) {
        if (ks + 1 < HD / 32)
            gload_lds16(gsrc + (ks + 1) * 32, (char*)(sA ? As[cur ^ 1] : Bs[cur ^ 1]) + ldsoff);
        const int arow = wr * 16 + (lane & 15);
        const int brow = wc * 16 + (lane & 15);
        const int g = lane >> 4;
        bf16x8 a = *(const bf16x8*)((const char*)As[cur] + arow * 64 + ((g ^ ((arow >> 1) & 3)) << 4));
        bf16x8 b = *(const bf16x8*)((const char*)Bs[cur] + brow * 64 + ((g ^ ((brow >> 1) & 3)) << 4));
        acc = __builtin_amdgcn_mfma_f32_16x16x32_bf16(a, b, acc, 0, 0, 0);
        __syncthreads();                             // drains stage (vm) + reads (lgkm)
        cur ^= 1;
    }

    // scatter gates: lane col p = wc*16+(lane&15) -> unit p>>2, gate p&3
    const int p  = wc * 16 + (lane & 15);
    const int uu = p >> 2, gg = p & 3;
    #pragma unroll
    for (int q = 0; q < 4; ++q)
        gsm[gg][wr * 16 + (lane >> 4) * 4 + q][uu] = acc[q];
    __syncthreads();

    // fused LSTM elementwise: 32 rows x 8 units = 256 elems, 1 per thread
    const int m = tid >> 3, u8 = tid & 7;
    const int r = m0 + m, u = blockIdx.x * 8 + u8;
    size_t pb = (size_t)r * G4 + u;
    float gi = gsm[0][m][u8] + pre_t[pb]          + gctx[pb];
    float gf = gsm[1][m][u8] + pre_t[pb + HD]     + gctx[pb + HD];
    float gg2 = gsm[2][m][u8] + pre_t[pb + 2 * HD] + gctx[pb + 2 * HD];
    float go = gsm[3][m][u8] + pre_t[pb + 3 * HD] + gctx[pb + 3 * HD];
    float si = 1.f / (1.f + expf(-gi));
    float sf = 1.f / (1.f + expf(-gf));
    float so = 1.f / (1.f + expf(-go));
    float cn = sf * cbuf[(size_t)r * HD + u] + si * tanhf(gg2);
    float hn = so * tanhf(cn);
    cbuf[(size_t)r * HD + u] = cn;
    short hb = (short)f2bf(hn);
    Hnext[(size_t)r * HD + u]  = hb;
    Hall_t[(size_t)r * HD + u] = hb;
}

// ---------------- fused log_softmax + softmax over V ----------------
__global__ void softmax_kernel(float* __restrict__ words_logout, float* __restrict__ smout) {
    int r = blockIdx.x;            // T*B rows
    int tid = threadIdx.x;         // 512
    float* row = words_logout + (size_t)r * VV;
    __shared__ float red[512];
    float m = -1e30f;
    for (int i = tid; i < VV; i += 512) m = fmaxf(m, row[i]);
    red[tid] = m; __syncthreads();
    for (int s = 256; s > 0; s >>= 1) { if (tid < s) red[tid] = fmaxf(red[tid], red[tid + s]); __syncthreads(); }
    m = red[0]; __syncthreads();
    float sum = 0.f;
    for (int i = tid; i < VV; i += 512) sum += expf(row[i] - m);
    red[tid] = sum; __syncthreads();
    for (int s = 256; s > 0; s >>= 1) { if (tid < s) red[tid] += red[tid + s]; __syncthreads(); }
    sum = red[0];
    float lz = logf(sum);
    for (int i = tid; i < VV; i += 512) {
        float x = row[i];
        float e = expf(x - m);
        smout[(size_t)r * VV + i] = e / sum;
        row[i] = x - m - lz;
    }
}

// ---------------- launch ----------------
extern "C" void kernel_launch(void* const* d_in, const int* in_sizes, int n_in,
                              void* d_out, int out_size, void* d_ws, size_t ws_size,
                              hipStream_t stream) {
    const float* features    = (const float*)d_in[0];
    const int*   captions    = (const int*)  d_in[1];
    const float* W_init_h    = (const float*)d_in[2];
    const float* W_init_c    = (const float*)d_in[3];
    const float* W_attn_v    = (const float*)d_in[4];
    const float* b_attn_v    = (const float*)d_in[5];
    // d_in[6], d_in[7] (W_attn_h, b_attn_h) dead: softmax shift-invariance.
    const float* embed_table = (const float*)d_in[8];
    const float* W_ih        = (const float*)d_in[9];
    const float* W_hh        = (const float*)d_in[10];
    const float* b_ih        = (const float*)d_in[11];
    const float* b_hh        = (const float*)d_in[12];
    const float* W_out       = (const float*)d_in[13];
    const float* b_out       = (const float*)d_in[14];

    float* out   = (float*)d_out;
    float* words = out;                        // first half (log_softmax in place)
    float* s2    = out + (size_t)TT * B * VV;  // second half: scratch until final softmax

    // second-half scratch — byte-identical layout to the passing binary (FROZEN)
    float* gate_pre = s2;                                        // 10,485,760 f
    short* Hall_b   = (short*)(s2 + (size_t)10485760);           // TT x B*HD bf16
    short* Wout_b   = (short*)(s2 + (size_t)10485760 + 1310720); // VPAD*HD
    short* Wih_b    = Wout_b + (size_t)VPAD * HD;
    short* Whh_b    = Wih_b  + (size_t)G4 * HD;                  // PERMUTED W_hh
    short* Wini_h_b = Whh_b  + (size_t)G4 * HD;
    short* Wini_c_b = Wini_h_b + (size_t)HD * DV;

    // ws small scratch
    char* w = (char*)d_ws;
    size_t off = 0;
    auto alloc = [&](size_t bytes) { void* p = w + off; off = (off + bytes + 255) & ~255UL; return p; };
    float* attv   = (float*)alloc((size_t)B * NLOC * 4);
    float* alpha  = (float*)alloc((size_t)B * NLOC * 4);
    float* gctx   = (float*)alloc((size_t)B * G4 * 4);
    float* h0f    = (float*)alloc((size_t)B * HD * 4);
    float* cbuf   = (float*)alloc((size_t)B * HD * 4);
    short* fmean_b= (short*)alloc((size_t)B * DV * 2);
    short* ctx_b  = (short*)alloc((size_t)B * DV * 2);
    short* h_ping = (short*)alloc((size_t)B * HD * 2);
    short* h_pong = (short*)alloc((size_t)B * HD * 2);
    short* emb_b  = (short*)alloc((size_t)TT * B * EMB * 2);

    // ---- weight conversions (identical) ----
    f2bf_pad_kernel<<<((size_t)VPAD * HD + 255) / 256, 256, 0, stream>>>(
        W_out, Wout_b, (size_t)VV * HD, (size_t)VPAD * HD);
    f2bf_pad_kernel<<<((size_t)G4 * HD + 255) / 256, 256, 0, stream>>>(
        W_ih, Wih_b, (size_t)G4 * HD, (size_t)G4 * HD);
    whh_perm_kernel<<<((size_t)G4 * HD + 255) / 256, 256, 0, stream>>>(W_hh, Whh_b);
    f2bf_pad_kernel<<<((size_t)HD * DV + 255) / 256, 256, 0, stream>>>(
        W_init_h, Wini_h_b, (size_t)HD * DV, (size_t)HD * DV);
    f2bf_pad_kernel<<<((size_t)HD * DV + 255) / 256, 256, 0, stream>>>(
        W_init_c, Wini_c_b, (size_t)HD * DV, (size_t)HD * DV);

    // ---- phase 1: time-parallel (identical) ----
    fmean_kernel<<<(B * DV + 255) / 256, 256, 0, stream>>>(features, fmean_b);
    attv_kernel<<<B * NLOC, 64, 0, stream>>>(features, W_attn_v, b_attn_v, attv);
    alpha_kernel<<<B, 256, 0, stream>>>(attv, alpha);
    ctx_kernel<<<(B * DV + 255) / 256, 256, 0, stream>>>(features, alpha, ctx_b);
    emb_gather_kernel<<<((size_t)TT * B * EMB + 255) / 256, 256, 0, stream>>>(captions, embed_table, emb_b);

    // h0 / c0 (identical)
    gemm_bf16<32, 4, 1><<<dim3(HD / 32, 1), 256, 0, stream>>>(
        fmean_b, Wini_h_b, h0f, nullptr, nullptr, B, HD, DV, DV, DV, HD);
    gemm_bf16<32, 4, 1><<<dim3(HD / 32, 1), 256, 0, stream>>>(
        fmean_b, Wini_c_b, cbuf, nullptr, nullptr, B, HD, DV, DV, DV, HD);
    hcvt_kernel<<<(B * HD + 255) / 256, 256, 0, stream>>>(h0f, h_ping);

    // gctx / gate_pre (identical call-sites)
    gemm_bf16<32, 4, 1><<<dim3(G4 / 32, 1), 256, 0, stream>>>(
        ctx_b, Wih_b, gctx, b_ih, b_hh, B, G4, DV, DV, HD, G4);
    gemm_bf16<128, 2, 2><<<dim3(G4 / 128, TT * B / 128), 256, 0, stream>>>(
        emb_b, Wih_b + DV, gate_pre, nullptr, nullptr, TT * B, G4, EMB, EMB, DV + EMB, G4);

    // ---- phase 2: fused recurrence (pipelined step kernel — THE delta) ----
    for (int t = 0; t < TT; ++t) {
        lstm_step3<<<dim3(HD / 8, B / 32), 256, 0, stream>>>(
            (t & 1) ? h_pong : h_ping, Whh_b, gate_pre + (size_t)t * B * G4, gctx,
            cbuf, (t & 1) ? h_ping : h_pong, Hall_b + (size_t)t * BH);
    }

    // ---- phase 3: words = Hall @ W_out^T + b_out (identical) ----
    gemm_bf16<128, 2, 2><<<dim3(VPAD / 128, TT * B / 128), 256, 0, stream>>>(
        Hall_b, Wout_b, words, b_out, nullptr, TT * B, VV, HD, HD, HD, VV);
    softmax_kernel<<<TT * B, 512, 0, stream>>>(words, s2);
}